// Round 4
// baseline (489.477 us; speedup 1.0000x reference)
//
#include <hip/hip_runtime.h>

#define HH 192
#define WW 192
#define HWPIX (HH * WW)
#define NPIX 324            // 18x18 halo tile
#define PLANE 5184          // NPIX*16 bytes per c-slot plane
#define CHUNKB 20736        // NPIX*64 bytes per 32c chunk

typedef __attribute__((ext_vector_type(8))) short bf16x8;
typedef __attribute__((ext_vector_type(4))) float f32x4;

__device__ __forceinline__ unsigned short f2bf(float f) {
    unsigned u = __builtin_bit_cast(unsigned, f);
    return (unsigned short)((u + 0x7FFFu + ((u >> 16) & 1u)) >> 16);
}

// ---------------- weight fusion ----------------
// wbuf shorts: (((cc*9+tap)*8 + ot)*64 + ln)*8 + j ; ot=o>>4, ln=((c>>3)&3)*16+(o&15), j=c&7
__global__ void fuse_weights(const float* __restrict__ wsq, const float* __restrict__ wv,
                             const float* __restrict__ whr, const float* __restrict__ w19,
                             const float* __restrict__ w37, unsigned short* __restrict__ wbuf) {
    int idx = blockIdx.x * 256 + threadIdx.x;
    if (idx >= 128 * 128 * 9) return;
    int o = idx / 1152;
    int r = idx - o * 1152;
    int c = r / 9;
    int tap = r - c * 9;
    int kh = tap / 3, kw = tap - kh * 3;
    float v = wsq[((o * 128 + c) * 3 + kh) * 3 + kw];
    if (kw == 1) v += wv[(o * 128 + c) * 3 + kh];
    if (kh == 1) v += whr[(o * 128 + c) * 3 + kw];
    if (kh == kw) v += w19[((o * 128 + c) * 3 + kh) * 3 + kw];
    if (kh + kw == 2) v += w37[((o * 128 + c) * 3 + kh) * 3 + kw];
    int cc = c >> 5, ot = o >> 4;
    int ln = ((c >> 3) & 3) * 16 + (o & 15);
    int j = c & 7;
    wbuf[(((cc * 9 + tap) * 8 + ot) * 64 + ln) * 8 + j] = f2bf(v);
}

// ---------------- single-pass conv ----------------
// Block: 16x16 output tile, all 128 o. 4 waves = (mi: o-half, ni: row-half).
// K-loop: 4 chunks of 32 c. Staging: fp32 NCHW -> regs -> cvt -> LDS bf16,
// slot-plane layout addr = (c>>3)*PLANE + pix*16 + (c&7)*2; 16-lane groups read
// 256B contiguous -> conflict-free. OOB halo handled by writing 0 in the
// convert pass itself (no separate zeroing pass -> no write/zero race).
__global__ __launch_bounds__(256) void conv1p(const float* __restrict__ x,
                                              const unsigned short* __restrict__ wbuf,
                                              float* __restrict__ out) {
    __shared__ __align__(1024) unsigned char lds[2 * CHUNKB];
    const int t = threadIdx.x;
    const int l = t & 63;
    const int wvid = t >> 6;
    const int mi = wvid >> 1, ni = wvid & 1;
    const int l15 = l & 15, l4 = l >> 4;

    // XCD-chunked bijective swizzle: 2304 blocks, 288 per XCD = 2 full batches.
    int id = (int)blockIdx.x;
    int id2 = (id & 7) * 288 + (id >> 3);
    int b = id2 / 144;
    int rem = id2 - b * 144;
    int by = rem / 12;
    int bx = rem - by * 12;
    const int h0 = by * 16, w0 = bx * 16;

    const float* __restrict__ xb = x + (size_t)b * (128 * HWPIX);

    f32x4 acc[4][8];
    const f32x4 zero = {0.f, 0.f, 0.f, 0.f};
#pragma unroll
    for (int mo = 0; mo < 4; ++mo)
#pragma unroll
        for (int np = 0; np < 8; ++np) acc[mo][np] = zero;

    const int rbase = l4 * PLANE + (ni * 144 + l15) * 16;

    // staging: 32c x 18h x 6 f32x4 (w in [w0-4, w0+20), clamped) = 3456 items
    f32x4 vs[14];

#define STAGE_LOAD(CC)                                                                  \
    _Pragma("unroll") for (int i = 0; i < 14; ++i) {                                    \
        if (i < 13 || t < 128) {                                                        \
            int u = t + 256 * i;                                                        \
            int c = u / 108;                                                            \
            int r = u - c * 108;                                                        \
            int ih = r / 6;                                                             \
            int f = r - ih * 6;                                                         \
            int gh = h0 - 1 + ih; gh = min(max(gh, 0), HH - 1);                         \
            int wb = w0 - 4 + 4 * f; wb = min(max(wb, 0), WW - 4);                      \
            vs[i] = *(const f32x4*)(xb + (size_t)((CC) * 32 + c) * HWPIX + gh * WW + wb); \
        }                                                                               \
    }

// Convert + write, with OOB -> 0 folded in. Whenever the load above was
// clamped, the corresponding (gh,gw) target is out of range and gets 0,
// so clamped garbage never lands in a live halo slot.
#define STAGE_WRITE(BB)                                                                 \
    _Pragma("unroll") for (int i = 0; i < 14; ++i) {                                    \
        if (i < 13 || t < 128) {                                                        \
            int u = t + 256 * i;                                                        \
            int c = u / 108;                                                            \
            int r = u - c * 108;                                                        \
            int ih = r / 6;                                                             \
            int f = r - ih * 6;                                                         \
            int gh = h0 - 1 + ih;                                                       \
            bool hok = (unsigned)gh < (unsigned)HH;                                     \
            unsigned char* wp = lds + (BB) + (c >> 3) * PLANE + (c & 7) * 2;            \
            _Pragma("unroll") for (int e = 0; e < 4; ++e) {                             \
                int iw = 4 * f + e - 3;                                                 \
                int gw = w0 - 4 + 4 * f + e;                                            \
                if ((unsigned)iw < 18u) {                                               \
                    unsigned short val =                                                \
                        (hok && (unsigned)gw < (unsigned)WW) ? f2bf(vs[i][e])           \
                                                             : (unsigned short)0;      \
                    *(unsigned short*)(wp + (ih * 18 + iw) * 16) = val;                 \
                }                                                                       \
            }                                                                           \
        }                                                                               \
    }

    STAGE_LOAD(0)
    STAGE_WRITE(0)
    __syncthreads();

    int bb = 0;
#pragma unroll 1
    for (int cc = 0; cc < 4; ++cc) {
        if (cc < 3) STAGE_LOAD(cc + 1)

        // ---- compute chunk cc from buffer bb; taps unrolled, one-tap-ahead
        //      weight prefetch caps live weight regs at 2x16 ----
        const unsigned short* wbase = wbuf + (size_t)cc * 36864 + (size_t)(mi * 4 * 64 + l) * 8;
        bf16x8 a_cur[4], a_nxt[4];
#pragma unroll
        for (int mo = 0; mo < 4; ++mo) a_cur[mo] = *(const bf16x8*)(wbase + mo * 512);
#pragma unroll
        for (int tap = 0; tap < 9; ++tap) {
            const int kh = tap / 3, kw = tap - kh * 3;
            if (tap < 8) {
#pragma unroll
                for (int mo = 0; mo < 4; ++mo)
                    a_nxt[mo] = *(const bf16x8*)(wbase + ((tap + 1) * 8 + mo) * 512);
            }
#pragma unroll
            for (int np = 0; np < 8; ++np) {
                const int off = ((np + kh) * 18 + kw) * 16;
                bf16x8 bf = *(const bf16x8*)(lds + bb + rbase + off);
#pragma unroll
                for (int mo = 0; mo < 4; ++mo)
                    acc[mo][np] = __builtin_amdgcn_mfma_f32_16x16x32_bf16(a_cur[mo], bf, acc[mo][np], 0, 0, 0);
            }
#pragma unroll
            for (int mo = 0; mo < 4; ++mo) a_cur[mo] = a_nxt[mo];
        }

        if (cc < 3) STAGE_WRITE(bb ^ CHUNKB)
        __syncthreads();
        bb ^= CHUNKB;
    }

    // ---- epilogue: D row=(l>>4)*4+j -> o, col=l&15 -> w ----
    float* __restrict__ ob = out + (size_t)b * (128 * HWPIX) + (size_t)h0 * WW + w0 + l15;
#pragma unroll
    for (int mo = 0; mo < 4; ++mo) {
#pragma unroll
        for (int j = 0; j < 4; ++j) {
            int o = mi * 64 + mo * 16 + l4 * 4 + j;
            float* op = ob + (size_t)o * HWPIX;
#pragma unroll
            for (int np = 0; np < 8; ++np)
                op[(ni * 8 + np) * WW] = acc[mo][np][j];
        }
    }
}

extern "C" void kernel_launch(void* const* d_in, const int* in_sizes, int n_in,
                              void* d_out, int out_size, void* d_ws, size_t ws_size,
                              hipStream_t stream) {
    const float* x   = (const float*)d_in[0];
    const float* wsq = (const float*)d_in[1];
    const float* wv  = (const float*)d_in[2];
    const float* wh  = (const float*)d_in[3];
    const float* w19 = (const float*)d_in[4];
    const float* w37 = (const float*)d_in[5];
    unsigned short* wbuf = (unsigned short*)d_ws;  // 294,912 B

    fuse_weights<<<576, 256, 0, stream>>>(wsq, wv, wh, w19, w37, wbuf);
    conv1p<<<2304, 256, 0, stream>>>(x, wbuf, (float*)d_out);
}

// Round 5
// 357.614 us; speedup vs baseline: 1.3687x; 1.3687x over previous
//
#include <hip/hip_runtime.h>

#define HH 192
#define WW 192
#define HWPIX (HH * WW)
#define PH 194                     // padded dim (zero ring of 1)
#define PLANE 5184                 // 324 halo px * 16B per slot-plane in LDS
#define CHUNKB 20736               // 4 slot-planes per 32c chunk
#define PSHORTS (PH * PH * 8)      // 301088 shorts per xn slot-plane
#define RSHORTS (PH * 8)           // 1552 shorts per padded row

typedef __attribute__((ext_vector_type(8))) short bf16x8;
typedef __attribute__((ext_vector_type(8))) unsigned short u16x8;
typedef __attribute__((ext_vector_type(4))) float f32x4;

__device__ __forceinline__ unsigned short f2bf(float f) {
    unsigned u = __builtin_bit_cast(unsigned, f);
    return (unsigned short)((u + 0x7FFFu + ((u >> 16) & 1u)) >> 16);
}

__device__ __forceinline__ void gload_lds16(const void* g, void* l) {
    __builtin_amdgcn_global_load_lds((const __attribute__((address_space(1))) void*)g,
                                     (__attribute__((address_space(3))) void*)l, 16, 0, 0);
}

// ---------------- weight fusion ----------------
// frag = ((cc*3 + kw)*2 + mi)*12 + kh*4 + mo ; within frag: ln*8 + j
// mi=o>>6, mo=(o>>4)&3, ln=((c>>3)&3)*16+(o&15), j=c&7, cc=c>>5
__global__ void fuse_weights(const float* __restrict__ wsq, const float* __restrict__ wv,
                             const float* __restrict__ whr, const float* __restrict__ w19,
                             const float* __restrict__ w37, unsigned short* __restrict__ wbuf) {
    int idx = blockIdx.x * 256 + threadIdx.x;
    if (idx >= 128 * 128 * 9) return;
    int o = idx / 1152;
    int r = idx - o * 1152;
    int c = r / 9;
    int tap = r - c * 9;
    int kh = tap / 3, kw = tap - kh * 3;
    float v = wsq[((o * 128 + c) * 3 + kh) * 3 + kw];
    if (kw == 1) v += wv[(o * 128 + c) * 3 + kh];
    if (kh == 1) v += whr[(o * 128 + c) * 3 + kw];
    if (kh == kw) v += w19[((o * 128 + c) * 3 + kh) * 3 + kw];
    if (kh + kw == 2) v += w37[((o * 128 + c) * 3 + kh) * 3 + kw];
    int cc = c >> 5;
    int mi = o >> 6, mo = (o >> 4) & 3;
    int ln = ((c >> 3) & 3) * 16 + (o & 15);
    int j = c & 7;
    int frag = ((cc * 3 + kw) * 2 + mi) * 12 + kh * 4 + mo;
    wbuf[(size_t)frag * 512 + ln * 8 + j] = f2bf(v);
}

// ---------------- pass 1: NCHW fp32 -> padded blocked-planar bf16 ----------------
// xn[bh][slot 16][ph 194][pw 194][8c], zero ring at ph/pw in {0,193}.
__global__ __launch_bounds__(256) void to_xn(const float* __restrict__ x,
                                             unsigned short* __restrict__ xn, int b0) {
    const int ph = blockIdx.x;      // 0..193
    const int bh = blockIdx.y;      // 0..7
    const int b = b0 + bh;
    const int t = threadIdx.x;
    unsigned short* __restrict__ xnb = xn + (size_t)bh * 16 * PSHORTS;
    const u16x8 z = {0, 0, 0, 0, 0, 0, 0, 0};

    if (ph == 0 || ph == PH - 1) {  // zero top/bottom rows, all 16 slots
#pragma unroll 1
        for (int s = 0; s < 16; ++s)
            if (t < PH)
                *(u16x8*)(xnb + (size_t)s * PSHORTS + (size_t)ph * RSHORTS + t * 8) = z;
        return;
    }
    if (t < 32) {                   // zero left/right pad pixels of this row
        int s = t >> 1;
        int pw = (t & 1) * (PH - 1);
        *(u16x8*)(xnb + (size_t)s * PSHORTS + (size_t)ph * RSHORTS + pw * 8) = z;
    }
    const int h = ph - 1;
    const int wq = t & 15;
    const int s = t >> 4;
    const float* __restrict__ xb = x + ((size_t)b * 128 + s * 8) * HWPIX + h * WW;
    unsigned short* __restrict__ xr = xnb + (size_t)s * PSHORTS + (size_t)ph * RSHORTS + 8;
#pragma unroll 1
    for (int wc = 0; wc < 3; ++wc) {
        int w = wc * 64 + wq * 4;
        f32x4 v[8];
#pragma unroll
        for (int j = 0; j < 8; ++j) v[j] = *(const f32x4*)(xb + (size_t)j * HWPIX + w);
#pragma unroll
        for (int e = 0; e < 4; ++e) {
            u16x8 ov;
#pragma unroll
            for (int j = 0; j < 8; ++j) ov[j] = f2bf(v[j][e]);
            *(u16x8*)(xr + (w + e) * 8) = ov;
        }
    }
}

// ---------------- pass 2: conv via MFMA ----------------
// Block: 16x16 out px, 128 o, 4 waves = (mi: o-half, ni: row-half).
// Chunk = 32c staged by global_load_lds into slot-plane layout (wave wv
// stages slot wv; dest = uniform base + lane*16 linear). Compute: kw-outer
// passes; frag(row,kw) reused by all kh (np=row-kh): 30 ds_read_b128 +
// 288 MFMA + 36 weight loads per wave-chunk.
__global__ __launch_bounds__(256) void convp(const unsigned short* __restrict__ xn,
                                             const unsigned short* __restrict__ wbuf,
                                             float* __restrict__ out, int b0) {
    __shared__ __align__(1024) unsigned char lds[2 * CHUNKB];
    const int t = threadIdx.x, l = t & 63, wv = t >> 6;
    const int mi = wv >> 1, ni = wv & 1, l15 = l & 15, l4 = l >> 4;

    // per-XCD = per-batch swizzle: 1152 blocks = 8 batches x 144 tiles
    int id = (int)blockIdx.x;
    int id2 = (id & 7) * 144 + (id >> 3);
    int bh = id2 / 144;
    int rem = id2 - bh * 144;
    int by = rem / 12, bx = rem - by * 12;
    const int h0 = by * 16, w0 = bx * 16;

    f32x4 acc[4][8];
    const f32x4 zero = {0.f, 0.f, 0.f, 0.f};
#pragma unroll
    for (int mo = 0; mo < 4; ++mo)
#pragma unroll
        for (int np = 0; np < 8; ++np) acc[mo][np] = zero;

#define STAGE(CC, BB)                                                                    \
    {                                                                                    \
        const unsigned short* sb = xn + ((size_t)(bh * 16 + (CC) * 4 + wv)) * PSHORTS +  \
                                   (size_t)h0 * RSHORTS + (size_t)w0 * 8;                \
        _Pragma("unroll") for (int i = 0; i < 6; ++i) {                                  \
            int p = i * 64 + l;                                                          \
            if (p < 324) {                                                               \
                int ih = p / 18, iw = p - ih * 18;                                       \
                gload_lds16(sb + ih * RSHORTS + iw * 8,                                  \
                            (void*)(lds + (BB) + wv * PLANE + i * 1024));                \
            }                                                                            \
        }                                                                                \
    }

    STAGE(0, 0);
    __syncthreads();

    int bb = 0;
#pragma unroll 1
    for (int cc = 0; cc < 4; ++cc) {
        if (cc < 3) STAGE(cc + 1, bb ^ CHUNKB);

        const int rdbase = bb + l4 * PLANE + (ni * 8 * 18 + l15) * 16;
#pragma unroll 1
        for (int kw = 0; kw < 3; ++kw) {
            const unsigned short* wp =
                wbuf + (size_t)(((cc * 3 + kw) * 2 + mi) * 12) * 512 + l * 8;
            bf16x8 a[12];
#pragma unroll
            for (int f = 0; f < 12; ++f) a[f] = *(const bf16x8*)(wp + f * 512);
#pragma unroll
            for (int rr = 0; rr < 10; ++rr) {
                bf16x8 bf = *(const bf16x8*)(lds + rdbase + kw * 16 + rr * 288);
#pragma unroll
                for (int kh = 0; kh < 3; ++kh) {
                    const int np = rr - kh;
                    if (np >= 0 && np < 8) {
#pragma unroll
                        for (int mo = 0; mo < 4; ++mo)
                            acc[mo][np] = __builtin_amdgcn_mfma_f32_16x16x32_bf16(
                                a[kh * 4 + mo], bf, acc[mo][np], 0, 0, 0);
                    }
                }
            }
        }
        __syncthreads();
        bb ^= CHUNKB;
    }

    // epilogue: D row=(l>>4)*4+j -> o_low, col=l&15 -> w
    const int b = b0 + bh;
    float* __restrict__ ob = out + (size_t)b * (128 * HWPIX) + (size_t)h0 * WW + w0 + l15;
#pragma unroll
    for (int mo = 0; mo < 4; ++mo) {
#pragma unroll
        for (int j = 0; j < 4; ++j) {
            int o = mi * 64 + mo * 16 + l4 * 4 + j;
            float* op = ob + (size_t)o * HWPIX;
#pragma unroll
            for (int np = 0; np < 8; ++np)
                op[(ni * 8 + np) * WW] = acc[mo][np][j];
        }
    }
}

extern "C" void kernel_launch(void* const* d_in, const int* in_sizes, int n_in,
                              void* d_out, int out_size, void* d_ws, size_t ws_size,
                              hipStream_t stream) {
    const float* x   = (const float*)d_in[0];
    const float* wsq = (const float*)d_in[1];
    const float* wvv = (const float*)d_in[2];
    const float* wh  = (const float*)d_in[3];
    const float* w19 = (const float*)d_in[4];
    const float* w37 = (const float*)d_in[5];

    unsigned short* wbuf = (unsigned short*)d_ws;                      // 294,912 B
    unsigned short* xn = (unsigned short*)((char*)d_ws + 294912);      // 77,078,528 B

    fuse_weights<<<576, 256, 0, stream>>>(wsq, wvv, wh, w19, w37, wbuf);

    for (int half = 0; half < 2; ++half) {
        to_xn<<<dim3(PH, 8), 256, 0, stream>>>(x, xn, half * 8);
        convp<<<1152, 256, 0, stream>>>(xn, wbuf, (float*)d_out, half * 8);
    }
}

// Round 7
// 269.784 us; speedup vs baseline: 1.8143x; 1.3256x over previous
//
#include <hip/hip_runtime.h>

#define HH 192
#define WW 192
#define HWPIX (HH * WW)
#define PLANE 5184           // 324 px * 16 B per c-octet plane
#define CHUNKB 20736         // 4 planes per 32c chunk

typedef __attribute__((ext_vector_type(8))) short bf16x8;
typedef __attribute__((ext_vector_type(4))) float f32x4;
typedef __attribute__((ext_vector_type(4))) unsigned int u32x4;

__device__ __forceinline__ unsigned f2bf(float f) {
    unsigned u = __builtin_bit_cast(unsigned, f);
    return (u + 0x7FFFu + ((u >> 16) & 1u)) >> 16;
}

// ---------------- weight fusion (round-5 layout, proven) ----------------
// frag = ((cc*3 + kw)*2 + mi)*12 + kh*4 + mo ; within frag: ln*8 + j
// mi=o>>6, mo=(o>>4)&3, ln=((c>>3)&3)*16+(o&15), j=c&7, cc=c>>5
__global__ void fuse_weights(const float* __restrict__ wsq, const float* __restrict__ wv,
                             const float* __restrict__ whr, const float* __restrict__ w19,
                             const float* __restrict__ w37, unsigned short* __restrict__ wbuf) {
    int idx = blockIdx.x * 256 + threadIdx.x;
    if (idx >= 128 * 128 * 9) return;
    int o = idx / 1152;
    int r = idx - o * 1152;
    int c = r / 9;
    int tap = r - c * 9;
    int kh = tap / 3, kw = tap - kh * 3;
    float v = wsq[((o * 128 + c) * 3 + kh) * 3 + kw];
    if (kw == 1) v += wv[(o * 128 + c) * 3 + kh];
    if (kh == 1) v += whr[(o * 128 + c) * 3 + kw];
    if (kh == kw) v += w19[((o * 128 + c) * 3 + kh) * 3 + kw];
    if (kh + kw == 2) v += w37[((o * 128 + c) * 3 + kh) * 3 + kw];
    int cc = c >> 5;
    int mi = o >> 6, mo = (o >> 4) & 3;
    int ln = ((c >> 3) & 3) * 16 + (o & 15);
    int j = c & 7;
    int frag = ((cc * 3 + kw) * 2 + mi) * 12 + kh * 4 + mo;
    wbuf[(size_t)frag * 512 + ln * 8 + j] = (unsigned short)f2bf(v);
}

// ---------------- single-pass conv ----------------
// Block: 16x16 out px, 128 o, 4 waves = (mi: o-half, ni: row-half).
// Staging (in-kernel transpose): thread owns whole pixels; 8 coalesced dword
// loads (c-planes), pack to bf16 pairs, ONE ds_write_b128 per pixel into
// [slot(c>>3)][px][8c] (lanes write consecutive 16B -> conflict-free).
// Two half-chunks interleaved between kw passes (load early / write late).
// Compute: round-5 kw-outer loop verbatim (proven correct).
__global__ __launch_bounds__(256, 2) void conv1(const float* __restrict__ x,
                                                const unsigned short* __restrict__ wbuf,
                                                float* __restrict__ out) {
    __shared__ __align__(1024) unsigned char lds[2 * CHUNKB];
    const int t = threadIdx.x, l = t & 63, wvid = t >> 6;
    const int mi = wvid >> 1, ni = wvid & 1, l15 = l & 15, l4 = l >> 4;

    // XCD-chunked bijective swizzle: 2304 = 8 x 288; 288/XCD = 2 full batches.
    int id = (int)blockIdx.x;
    int id2 = (id & 7) * 288 + (id >> 3);
    int b = id2 / 144;
    int rem = id2 - b * 144;
    int by = rem / 12, bx = rem - by * 12;
    const int h0 = by * 16, w0 = bx * 16;

    const float* __restrict__ xb = x + (size_t)b * (128 * HWPIX);

    f32x4 acc[4][8];
    const f32x4 zero = {0.f, 0.f, 0.f, 0.f};
#pragma unroll
    for (int mo = 0; mo < 4; ++mo)
#pragma unroll
        for (int np = 0; np < 8; ++np) acc[mo][np] = zero;

    float sv[4][8];
    int sok[4];

    // item = H*4+k in 0..7: slot = item>>1 (c-octet), px = (item&1)*256 + t
#define LOADH(CC, H)                                                                    \
    _Pragma("unroll") for (int k = 0; k < 4; ++k) {                                     \
        const int item = (H) * 4 + k;                                                   \
        const int slot = item >> 1;                                                     \
        int px = (item & 1) * 256 + t;                                                  \
        if (px < 324) {                                                                 \
            int ih = px / 18, iw = px - ih * 18;                                        \
            int gh = h0 - 1 + ih, gw = w0 - 1 + iw;                                     \
            sok[k] = ((unsigned)gh < (unsigned)HH) & ((unsigned)gw < (unsigned)WW);     \
            int ghc = min(max(gh, 0), HH - 1), gwc = min(max(gw, 0), WW - 1);           \
            const float* p = xb + (size_t)((CC) * 32 + slot * 8) * HWPIX + ghc * WW + gwc; \
            _Pragma("unroll") for (int j = 0; j < 8; ++j) sv[k][j] = p[j * HWPIX];      \
        }                                                                               \
    }

#define WRITEH(H, BB)                                                                   \
    _Pragma("unroll") for (int k = 0; k < 4; ++k) {                                     \
        const int item = (H) * 4 + k;                                                   \
        const int slot = item >> 1;                                                     \
        int px = (item & 1) * 256 + t;                                                  \
        if (px < 324) {                                                                 \
            u32x4 pk;                                                                   \
            _Pragma("unroll") for (int q = 0; q < 4; ++q) {                             \
                float lo = sok[k] ? sv[k][2 * q] : 0.f;                                 \
                float hi = sok[k] ? sv[k][2 * q + 1] : 0.f;                             \
                pk[q] = f2bf(lo) | (f2bf(hi) << 16);                                    \
            }                                                                           \
            *(u32x4*)(lds + (BB) + slot * PLANE + px * 16) = pk;                        \
        }                                                                               \
    }

#define KWPASS(KW)                                                                      \
    {                                                                                   \
        const unsigned short* wp =                                                      \
            wbuf + (size_t)(((cc * 3 + (KW)) * 2 + mi) * 12) * 512 + l * 8;             \
        bf16x8 a[12];                                                                   \
        _Pragma("unroll") for (int f = 0; f < 12; ++f)                                  \
            a[f] = *(const bf16x8*)(wp + f * 512);                                      \
        _Pragma("unroll") for (int rr = 0; rr < 10; ++rr) {                             \
            bf16x8 bf = *(const bf16x8*)(lds + rdbase + (KW) * 16 + rr * 288);          \
            _Pragma("unroll") for (int kh = 0; kh < 3; ++kh) {                          \
                const int np = rr - kh;                                                 \
                if (np >= 0 && np < 8) {                                                \
                    _Pragma("unroll") for (int mo = 0; mo < 4; ++mo)                    \
                        acc[mo][np] = __builtin_amdgcn_mfma_f32_16x16x32_bf16(          \
                            a[kh * 4 + mo], bf, acc[mo][np], 0, 0, 0);                  \
                }                                                                       \
            }                                                                           \
        }                                                                               \
    }

    // prologue: stage chunk 0 into buffer 0
    LOADH(0, 0)
    WRITEH(0, 0)
    LOADH(0, 1)
    WRITEH(1, 0)
    __syncthreads();

    int bb = 0;
#pragma unroll 1
    for (int cc = 0; cc < 4; ++cc) {
        const int rdbase = bb + l4 * PLANE + (ni * 144 + l15) * 16;
        if (cc < 3) { LOADH(cc + 1, 0) }
        KWPASS(0)
        if (cc < 3) {
            WRITEH(0, bb ^ CHUNKB)
            LOADH(cc + 1, 1)
        }
        KWPASS(1)
        if (cc < 3) { WRITEH(1, bb ^ CHUNKB) }
        KWPASS(2)
        __syncthreads();
        bb ^= CHUNKB;
    }

    // epilogue: D row=(l>>4)*4+j -> o_low, col=l&15 -> w  (round-5 verbatim)
    float* __restrict__ ob = out + (size_t)b * (128 * HWPIX) + (size_t)h0 * WW + w0 + l15;
#pragma unroll
    for (int mo = 0; mo < 4; ++mo) {
#pragma unroll
        for (int j = 0; j < 4; ++j) {
            int o = mi * 64 + mo * 16 + l4 * 4 + j;
            float* op = ob + (size_t)o * HWPIX;
#pragma unroll
            for (int np = 0; np < 8; ++np)
                op[(ni * 8 + np) * WW] = acc[mo][np][j];
        }
    }
}

extern "C" void kernel_launch(void* const* d_in, const int* in_sizes, int n_in,
                              void* d_out, int out_size, void* d_ws, size_t ws_size,
                              hipStream_t stream) {
    const float* x   = (const float*)d_in[0];
    const float* wsq = (const float*)d_in[1];
    const float* wvv = (const float*)d_in[2];
    const float* wh  = (const float*)d_in[3];
    const float* w19 = (const float*)d_in[4];
    const float* w37 = (const float*)d_in[5];

    unsigned short* wbuf = (unsigned short*)d_ws;  // 294,912 B

    fuse_weights<<<576, 256, 0, stream>>>(wsq, wvv, wh, w19, w37, wbuf);
    conv1<<<2304, 256, 0, stream>>>(x, wbuf, (float*)d_out);
}